// Round 1
// baseline (296.840 us; speedup 1.0000x reference)
//
#include <hip/hip_runtime.h>
#include <math.h>

#define HH 1024
#define WW 1024
#define NPLANES 12              // B*C = 4*3
#define PLANE (HH * WW)
#define NTOT (NPLANES * PLANE)  // 12,582,912
#define VTILE 32

struct W15 { float w[15]; };

// ---------------- Pass 1: fused pointwise chain ----------------
// white balance -> pow(gamma) -> shadow/highlight -> clip -> contrast/brightness -> clip
__global__ void k_point(const float4* __restrict__ x, float4* __restrict__ t0,
                        const float* __restrict__ gains,
                        const float* __restrict__ p_gamma,
                        const float* __restrict__ p_sb,
                        const float* __restrict__ p_hr,
                        const float* __restrict__ p_br,
                        const float* __restrict__ p_ct)
{
    int i = blockIdx.x * blockDim.x + threadIdx.x;
    if (i >= NTOT / 4) return;
    int plane = (i * 4) / PLANE;          // PLANE divisible by 4 -> uniform per float4
    int c = plane % 3;
    float gain  = gains[c];
    float gamma = *p_gamma;
    float sb    = *p_sb;
    float hr    = *p_hr;
    float br    = *p_br;
    float ct    = *p_ct;

    float4 v = x[i];
    float* pv = (float*)&v;
#pragma unroll
    for (int j = 0; j < 4; ++j) {
        float t = pv[j] * gain;
        t = powf(t, gamma);
        float hi = 1.0f / (1.0f + expf(-(t - 0.5f) * 10.0f));
        t = t + sb * (1.0f - hi) - hr * hi;
        t = fminf(fmaxf(t, 0.0f), 1.0f);
        t = ct * (t - 0.5f) + 0.5f + br;
        t = fminf(fmaxf(t, 0.0f), 1.0f);
        pv[j] = t;
    }
    t0[i] = v;
}

// ---------------- Horizontal 15-tap blur (zero pad), LDS staged ----------------
__global__ void k_hblur(const float* __restrict__ src, float* __restrict__ dst, W15 wk)
{
    __shared__ float sm[256 + 14];
    int p  = blockIdx.z;
    int y  = blockIdx.y;
    int x0 = blockIdx.x * 256;
    int t  = threadIdx.x;
    const float* row = src + (size_t)p * PLANE + (size_t)y * WW;

    for (int j = t; j < 256 + 14; j += 256) {
        int xg = x0 - 7 + j;
        sm[j] = (xg >= 0 && xg < WW) ? row[xg] : 0.0f;
    }
    __syncthreads();

    float acc = 0.0f;
#pragma unroll
    for (int k = 0; k < 15; ++k) acc += wk.w[k] * sm[t + k];
    dst[(size_t)p * PLANE + (size_t)y * WW + x0 + t] = acc;
}

// ---------------- Vertical blur + local-contrast fuse (in-place on A) ----------
// lm = vblur(B);  A[i] = (1+e)*A[i] - e*lm[i]
__global__ void k_vblur_lce(const float* __restrict__ srcB, float* __restrict__ ioA,
                            const float* __restrict__ p_enh, W15 wk)
{
    int p  = blockIdx.z;
    int x  = blockIdx.x * 256 + threadIdx.x;
    int y0 = blockIdx.y * VTILE;
    float e = *p_enh;

    const float* colB = srcB + (size_t)p * PLANE + x;
    float*       colA = ioA  + (size_t)p * PLANE + x;

    float win[15];
#pragma unroll
    for (int k = 0; k < 15; ++k) {
        int yy = y0 - 7 + k;
        win[k] = (yy >= 0 && yy < HH) ? colB[(size_t)yy * WW] : 0.0f;
    }

    for (int r = 0; r < VTILE; ++r) {
        int y = y0 + r;
        float lm = 0.0f;
#pragma unroll
        for (int k = 0; k < 15; ++k) lm += wk.w[k] * win[k];
        float t0v = colA[(size_t)y * WW];
        colA[(size_t)y * WW] = (1.0f + e) * t0v - e * lm;
#pragma unroll
        for (int k = 0; k < 14; ++k) win[k] = win[k + 1];
        int yn = y + 8;
        win[14] = (yn < HH) ? colB[(size_t)yn * WW] : 0.0f;
    }
}

// ---------------- Vertical blur + softness + gradient mask + clip -> out -------
// bl = vblur(B); v = s*bl + (1-s)*A; v = clip(v * (1 - intensity*sigmoid(-hard*rot_grid)))
__global__ void k_vblur_final(const float* __restrict__ srcB, const float* __restrict__ x2A,
                              float* __restrict__ out,
                              const float* __restrict__ p_soft,
                              const float* __restrict__ p_int,
                              const float* __restrict__ p_rot,
                              const float* __restrict__ p_hard,
                              W15 wk)
{
    int p  = blockIdx.z;
    int x  = blockIdx.x * 256 + threadIdx.x;
    int y0 = blockIdx.y * VTILE;

    float s     = *p_soft;
    float inten = *p_int;
    float rot   = *p_rot;
    float hard  = *p_hard;

    float theta = rot * 0.017453292519943295f;   // pi/180
    float cth = cosf(theta), sth = sinf(theta);
    float gx = -1.0f + 2.0f * (float)x / (float)(WW - 1);
    float base = gx * cth;

    const float* colB = srcB + (size_t)p * PLANE + x;
    const float* colA = x2A  + (size_t)p * PLANE + x;
    float*       colO = out  + (size_t)p * PLANE + x;

    float win[15];
#pragma unroll
    for (int k = 0; k < 15; ++k) {
        int yy = y0 - 7 + k;
        win[k] = (yy >= 0 && yy < HH) ? colB[(size_t)yy * WW] : 0.0f;
    }

    for (int r = 0; r < VTILE; ++r) {
        int y = y0 + r;
        float bl = 0.0f;
#pragma unroll
        for (int k = 0; k < 15; ++k) bl += wk.w[k] * win[k];
        float xv = colA[(size_t)y * WW];
        float v = s * bl + (1.0f - s) * xv;
        float gy = -1.0f + 2.0f * (float)y / (float)(HH - 1);
        float gr = base + gy * sth;
        float mask = 1.0f / (1.0f + expf(hard * gr));   // sigmoid(-hard*gr)
        v = v * (1.0f - inten * mask);
        v = fminf(fmaxf(v, 0.0f), 1.0f);
        colO[(size_t)y * WW] = v;
#pragma unroll
        for (int k = 0; k < 14; ++k) win[k] = win[k + 1];
        int yn = y + 8;
        win[14] = (yn < HH) ? colB[(size_t)yn * WW] : 0.0f;
    }
}

extern "C" void kernel_launch(void* const* d_in, const int* in_sizes, int n_in,
                              void* d_out, int out_size, void* d_ws, size_t ws_size,
                              hipStream_t stream)
{
    const float* x       = (const float*)d_in[0];
    const float* gains   = (const float*)d_in[1];
    const float* p_gamma = (const float*)d_in[2];
    const float* p_sb    = (const float*)d_in[3];
    const float* p_hr    = (const float*)d_in[4];
    const float* p_br    = (const float*)d_in[5];
    const float* p_ct    = (const float*)d_in[6];
    const float* p_enh   = (const float*)d_in[7];
    const float* p_soft  = (const float*)d_in[8];
    const float* p_int   = (const float*)d_in[9];
    const float* p_rot   = (const float*)d_in[10];
    const float* p_hard  = (const float*)d_in[11];

    float* A = (float*)d_out;   // t0 / x2 / final output (pointwise reuse is safe)
    float* B = (float*)d_ws;    // blur intermediates (needs NTOT*4 = 50.3 MB)

    // Gaussian weights (host-side, double precision; matches fp32 JAX to ~1e-8)
    W15 wk;
    {
        double g[15], sum = 0.0;
        for (int i = 0; i < 15; ++i) { double d = (double)(i - 7); g[i] = exp(-d * d / 18.0); sum += g[i]; }
        for (int i = 0; i < 15; ++i) wk.w[i] = (float)(g[i] / sum);
    }

    dim3 bp(256), gp((NTOT / 4 + 255) / 256);
    k_point<<<gp, bp, 0, stream>>>((const float4*)x, (float4*)A,
                                   gains, p_gamma, p_sb, p_hr, p_br, p_ct);

    dim3 bh(256), gh(WW / 256, HH, NPLANES);
    dim3 bv(256), gv(WW / 256, HH / VTILE, NPLANES);

    k_hblur<<<gh, bh, 0, stream>>>(A, B, wk);                      // B = hblur(t0)
    k_vblur_lce<<<gv, bv, 0, stream>>>(B, A, p_enh, wk);           // A = x2 (in place)
    k_hblur<<<gh, bh, 0, stream>>>(A, B, wk);                      // B = hblur(x2)
    k_vblur_final<<<gv, bv, 0, stream>>>(B, A, A,                  // A = final out
                                         p_soft, p_int, p_rot, p_hard, wk);
}

// Round 3
// 200.347 us; speedup vs baseline: 1.4816x; 1.4816x over previous
//
#include <hip/hip_runtime.h>
#include <math.h>

#define HH 1024
#define WW 1024
#define NPLANES 12              // B*C = 4*3
#define PLANE (HH * WW)
#define NTOT (NPLANES * PLANE)  // 12,582,912

#define TW 64                   // output tile width
#define TH 64                   // output tile height
#define HR 78                   // h-blurred rows needed = TH + 14
#define PADW 68                 // LDS row pitch (floats)

struct W15 { float w[15]; };

// ---------------- Pass 1: fused pointwise chain (fast-math transcendentals) ---
__global__ __launch_bounds__(256) void k_point(
    const float4* __restrict__ x, float4* __restrict__ o,
    const float* __restrict__ gains,
    const float* __restrict__ pg, const float* __restrict__ psb,
    const float* __restrict__ phr, const float* __restrict__ pbr,
    const float* __restrict__ pct)
{
    int i = blockIdx.x * blockDim.x + threadIdx.x;
    if (i >= NTOT / 4) return;
    int c = ((i * 4) / PLANE) % 3;           // PLANE % 4 == 0 -> uniform per float4
    float gain = gains[c];
    float gamma = *pg, sb = *psb, hr = *phr, br = *pbr, ct = *pct;

    float4 v = x[i];
    float* pv = (float*)&v;
#pragma unroll
    for (int j = 0; j < 4; ++j) {
        float t = pv[j] * gain;
        t = __builtin_amdgcn_exp2f(gamma * __log2f(t));        // pow(t,gamma), t>=0
        float hi = __fdividef(1.0f, 1.0f + __expf((0.5f - t) * 10.0f));
        t = t + sb * (1.0f - hi) - hr * hi;
        t = fminf(fmaxf(t, 0.0f), 1.0f);
        t = ct * (t - 0.5f) + 0.5f + br;
        t = fminf(fmaxf(t, 0.0f), 1.0f);
        pv[j] = t;
    }
    o[i] = v;
}

// ---------------- zero-padded aligned float4 row load -------------------------
__device__ inline float4 ld4z(const float* __restrict__ row, int x) {
    if (x >= 0 && x + 3 < WW) return *(const float4*)(row + x);
    float4 r; float* p = (float*)&r;
#pragma unroll
    for (int j = 0; j < 4; ++j) { int xx = x + j; p[j] = (xx >= 0 && xx < WW) ? row[xx] : 0.0f; }
    return r;
}

// ---------------- Fused separable 15x15 blur + epilogue -----------------------
// MODE 0: dst = (1+enh)*src - enh*blur(src)                  (local contrast)
// MODE 1: v = soft*blur(src) + (1-soft)*src; v *= (1 - inten*sigmoid(-hard*rot));
//         dst = clip(v)                                      (softness + gradient)
template<int MODE>
__global__ __launch_bounds__(256) void k_blur_fused(
    const float* __restrict__ src, float* __restrict__ dst,
    const float* __restrict__ s0, const float* __restrict__ s1,
    const float* __restrict__ s2, const float* __restrict__ s3, W15 wk)
{
    __shared__ float hbl[HR * PADW];
    const int p   = blockIdx.z;
    const int x0  = blockIdx.x * TW;
    const int y0  = blockIdx.y * TH;
    const int tid = threadIdx.x;
    const float* plane = src + (size_t)p * PLANE;

    // ---- Phase 1: horizontal blur -> LDS (4 cols/thread, registers only) ----
    {
        const int cx = (tid & 15) * 4;       // 0,4,...,60
        const int r0 = tid >> 4;             // 0..15
#pragma unroll
        for (int it = 0; it < 5; ++it) {
            int r = r0 + 16 * it;            // 0..79, need 0..77
            if (r < HR) {
                int y = y0 - 7 + r;
                float4 o;
                if (y >= 0 && y < HH) {
                    const float* row = plane + (size_t)y * WW;
                    int xb = x0 + cx - 8;    // aligned (mult of 4)
                    float f[20];
                    *(float4*)&f[0]  = ld4z(row, xb);
                    *(float4*)&f[4]  = ld4z(row, xb + 4);
                    *(float4*)&f[8]  = ld4z(row, xb + 8);
                    *(float4*)&f[12] = ld4z(row, xb + 12);
                    *(float4*)&f[16] = ld4z(row, xb + 16);
                    float* po = (float*)&o;
#pragma unroll
                    for (int j = 0; j < 4; ++j) {
                        float acc = 0.0f;
#pragma unroll
                        for (int k = 0; k < 15; ++k) acc += wk.w[k] * f[j + 1 + k];
                        po[j] = acc;
                    }
                } else {
                    o = make_float4(0.0f, 0.0f, 0.0f, 0.0f);   // zero padding rows
                }
                *(float4*)&hbl[r * PADW + cx] = o;
            }
        }
    }
    __syncthreads();

    // ---- Phase 2: vertical blur (register sliding window) + epilogue --------
    const int tx  = tid & 63;
    const int ty  = tid >> 6;                // 0..3 (one wave each)
    const int ly0 = ty * 16;
    const int x   = x0 + tx;

    float win[15];
#pragma unroll
    for (int k = 0; k < 15; ++k) win[k] = hbl[(ly0 + k) * PADW + tx];

    float a0 = *s0;                          // enh | soft
    float a1 = 0.f, sth = 0.f, hard = 0.f, base = 0.f;
    if (MODE == 1) {
        a1 = *s1;                            // intensity
        float theta = (*s2) * 0.017453292519943295f;
        float cth = __cosf(theta); sth = __sinf(theta);
        hard = *s3;
        float gx = -1.0f + 2.0f * (float)x * (1.0f / (float)(WW - 1));
        base = gx * cth;
    }

    float* dstP = dst + (size_t)p * PLANE;

#pragma unroll
    for (int j = 0; j < 16; ++j) {
        int y = y0 + ly0 + j;
        float bl = 0.0f;
#pragma unroll
        for (int k = 0; k < 15; ++k) bl += wk.w[k] * win[k];
        float c = plane[(size_t)y * WW + x];   // center (same buffer as blur src)
        float v;
        if (MODE == 0) {
            v = (1.0f + a0) * c - a0 * bl;
        } else {
            v = a0 * bl + (1.0f - a0) * c;
            float gy = -1.0f + 2.0f * (float)y * (1.0f / (float)(HH - 1));
            float gr = base + gy * sth;
            float mask = __fdividef(1.0f, 1.0f + __expf(hard * gr)); // sigmoid(-hard*gr)
            v = v * (1.0f - a1 * mask);
            v = fminf(fmaxf(v, 0.0f), 1.0f);
        }
        dstP[(size_t)y * WW + x] = v;
#pragma unroll
        for (int k = 0; k < 14; ++k) win[k] = win[k + 1];  // fully unrolled -> renamed
        win[14] = hbl[(ly0 + j + 15) * PADW + tx];
    }
}

extern "C" void kernel_launch(void* const* d_in, const int* in_sizes, int n_in,
                              void* d_out, int out_size, void* d_ws, size_t ws_size,
                              hipStream_t stream)
{
    const float* x       = (const float*)d_in[0];
    const float* gains   = (const float*)d_in[1];
    const float* p_gamma = (const float*)d_in[2];
    const float* p_sb    = (const float*)d_in[3];
    const float* p_hr    = (const float*)d_in[4];
    const float* p_br    = (const float*)d_in[5];
    const float* p_ct    = (const float*)d_in[6];
    const float* p_enh   = (const float*)d_in[7];
    const float* p_soft  = (const float*)d_in[8];
    const float* p_int   = (const float*)d_in[9];
    const float* p_rot   = (const float*)d_in[10];
    const float* p_hard  = (const float*)d_in[11];

    float* A = (float*)d_out;   // t0, then final output
    float* B = (float*)d_ws;    // x2 intermediate (50.3 MB)

    W15 wk;
    {
        double g[15], sum = 0.0;
        for (int i = 0; i < 15; ++i) { double d = (double)(i - 7); g[i] = exp(-d * d / 18.0); sum += g[i]; }
        for (int i = 0; i < 15; ++i) wk.w[i] = (float)(g[i] / sum);
    }

    // K1: pointwise chain  x -> A (t0)
    k_point<<<dim3(NTOT / 4 / 256), dim3(256), 0, stream>>>(
        (const float4*)x, (float4*)A, gains, p_gamma, p_sb, p_hr, p_br, p_ct);

    dim3 g(WW / TW, HH / TH, NPLANES);   // 16 x 16 x 12
    // K2: A (t0) -> B (x2 = (1+e)*t0 - e*blur(t0))
    k_blur_fused<0><<<g, dim3(256), 0, stream>>>(A, B, p_enh, p_enh, p_enh, p_enh, wk);
    // K3: B (x2) -> A (final: softness mix + gradient mask + clip)
    k_blur_fused<1><<<g, dim3(256), 0, stream>>>(B, A, p_soft, p_int, p_rot, p_hard, wk);
}